// Round 1
// baseline (1542.719 us; speedup 1.0000x reference)
//
#include <hip/hip_runtime.h>

// TT-LSTM: B=64, T=1024, D=H=256, F=16, R=16, NG=4.
// ws layout (floats):
//   A1ihT [64][256]  @ 0       ([g*16+s][m*16+n], composed g0*g1 for ih)
//   A1hT  [64][256]  @ 16384   (same for hh)
//   C2ih  [64][256]  @ 32768   ([g*16+s][o*16+p], composed g2*g3 for ih)
//   C2h   [64][256]  @ 49152
//   biasS [4][256]   @ 65536   (ih_bias + hh_bias)
//   T2ih  [65536][64]@ 66560   (first-stage ih contraction for all rows)
// total = 66560 + 4194304 floats = ~17.04 MB of ws.

#define WS_A1I 0
#define WS_A1H 16384
#define WS_C2I 32768
#define WS_C2H 49152
#define WS_BIAS 65536
#define WS_T2 66560

__device__ __forceinline__ float fsig(float x) {
    float e = __builtin_amdgcn_exp2f(-1.442695040888963f * x);
    return __builtin_amdgcn_rcpf(1.0f + e);
}
__device__ __forceinline__ float ftanh_(float x) {
    float e = __builtin_amdgcn_exp2f(2.885390081777926f * x);
    return 1.0f - 2.0f * __builtin_amdgcn_rcpf(1.0f + e);
}

// ---------------- K0: compose TT cores ----------------
__global__ void k_compose(const float* __restrict__ g0i, const float* __restrict__ g1i,
                          const float* __restrict__ g2i, const float* __restrict__ g3i,
                          const float* __restrict__ bi,
                          const float* __restrict__ g0h, const float* __restrict__ g1h,
                          const float* __restrict__ g2h, const float* __restrict__ g3h,
                          const float* __restrict__ bh,
                          float* __restrict__ ws) {
    int id = blockIdx.x * 256 + threadIdx.x;
    if (id < 16384) {
        // A1T[g*16+s][m*16+n] = sum_r g0[g][m][r] * g1[g][r][n][s]
        int g = id >> 12, s = (id >> 8) & 15, mn = id & 255;
        int m = mn >> 4, n = mn & 15;
        float aI = 0.f, aH = 0.f;
        for (int r = 0; r < 16; ++r) {
            aI += g0i[(g * 16 + m) * 16 + r] * g1i[((g * 16 + r) * 16 + n) * 16 + s];
            aH += g0h[(g * 16 + m) * 16 + r] * g1h[((g * 16 + r) * 16 + n) * 16 + s];
        }
        ws[WS_A1I + (g * 16 + s) * 256 + mn] = aI;
        ws[WS_A1H + (g * 16 + s) * 256 + mn] = aH;
    } else if (id < 32768) {
        // C2[g*16+s][o*16+p] = sum_t g2[g][s][o][t] * g3[g][t][p]
        int id2 = id - 16384;
        int g = id2 >> 12, s = (id2 >> 8) & 15, j = id2 & 255;
        int o = j >> 4, p = j & 15;
        float aI = 0.f, aH = 0.f;
        for (int t = 0; t < 16; ++t) {
            aI += g2i[((g * 16 + s) * 16 + o) * 16 + t] * g3i[(g * 16 + t) * 16 + p];
            aH += g2h[((g * 16 + s) * 16 + o) * 16 + t] * g3h[(g * 16 + t) * 16 + p];
        }
        ws[WS_C2I + (g * 16 + s) * 256 + j] = aI;
        ws[WS_C2H + (g * 16 + s) * 256 + j] = aH;
    } else if (id < 33792) {
        int id2 = id - 32768;
        ws[WS_BIAS + id2] = bi[id2] + bh[id2];
    }
}

// ---------------- K1: T2ih = X @ A1ih ----------------
// block = 256 threads, 64 rows; thread computes 4 rows x 4 outs.
__global__ __launch_bounds__(256, 1) void k_t2ih(const float* __restrict__ x,
                                                 const float* __restrict__ ws,
                                                 float* __restrict__ T2) {
    __shared__ __align__(16) float Xs[64 * 256];
    __shared__ __align__(16) float As[64 * 256];
    const int tid = threadIdx.x;
    const long r0 = (long)blockIdx.x * 64;

    // stage X tile and A1ih into LDS (A1 xor-swizzled on the f4-chunk index)
    const float4* X4 = (const float4*)(x + r0 * 256);
    const float4* A4 = (const float4*)(ws + WS_A1I);
    float4* Xs4 = (float4*)Xs;
    float4* As4 = (float4*)As;
#pragma unroll
    for (int k = 0; k < 16; ++k) {
        int idx = tid + k * 256;           // f4 index in [0,4096)
        Xs4[idx] = X4[idx];
        int row = idx >> 6, c = idx & 63;
        As4[(row << 6) | (c ^ (row & 15))] = A4[idx];
    }
    __syncthreads();

    const int ro = tid & 15;       // out group: outs ro*4..ro*4+3
    const int q  = tid >> 4;       // row group: rows q*4..q*4+3
    float acc[4][4];
#pragma unroll
    for (int i = 0; i < 4; ++i)
#pragma unroll
        for (int j = 0; j < 4; ++j) acc[i][j] = 0.f;

    for (int mn4 = 0; mn4 < 64; ++mn4) {
        float4 a[4], xv[4];
#pragma unroll
        for (int j = 0; j < 4; ++j) {
            int row = ro * 4 + j;
            a[j] = As4[(row << 6) | (mn4 ^ (row & 15))];
        }
#pragma unroll
        for (int i = 0; i < 4; ++i) xv[i] = Xs4[((q * 4 + i) << 6) | mn4];
#pragma unroll
        for (int i = 0; i < 4; ++i)
#pragma unroll
            for (int j = 0; j < 4; ++j)
                acc[i][j] += xv[i].x * a[j].x + xv[i].y * a[j].y +
                             xv[i].z * a[j].z + xv[i].w * a[j].w;
    }
#pragma unroll
    for (int i = 0; i < 4; ++i)
#pragma unroll
        for (int j = 0; j < 4; ++j)
            T2[(r0 + q * 4 + i) * 64 + ro * 4 + j] = acc[i][j];
}

// ---------------- K2: recurrent LSTM ----------------
// 64 blocks (one per batch row) x 256 threads, 1024 sequential steps.
__global__ __launch_bounds__(256, 1) void k_lstm(const float* __restrict__ ws,
                                                 const float* __restrict__ T2,
                                                 float* __restrict__ out) {
    __shared__ __align__(16) float hS[256];
    __shared__ __align__(16) float part[64 * 4];   // [out][q]
    __shared__ __align__(16) float t2hS[64];
    __shared__ __align__(16) float t2iS[2][64];

    const int tid = threadIdx.x;
    const int b = blockIdx.x;

    // ---- AB role: thread (abq = wave, abOut = lane) computes partial t2h[abOut]
    const int abq = tid >> 6;      // h-chunk: mn in [abq*64, abq*64+64)
    const int abOut = tid & 63;    // out = g*16+s

    // weight slices in registers
    float a1r[64];
    {
        const float4* A1h4 = (const float4*)(ws + WS_A1H);
#pragma unroll
        for (int k = 0; k < 16; ++k) {
            float4 v = A1h4[(abOut << 6) + (abq << 4) + k];
            a1r[4 * k + 0] = v.x; a1r[4 * k + 1] = v.y;
            a1r[4 * k + 2] = v.z; a1r[4 * k + 3] = v.w;
        }
    }
    float c2hr[64], c2ir[64], biasr[4];
#pragma unroll
    for (int u = 0; u < 64; ++u) {
        c2hr[u] = ws[WS_C2H + u * 256 + tid];
        c2ir[u] = ws[WS_C2I + u * 256 + tid];
    }
#pragma unroll
    for (int g = 0; g < 4; ++g) biasr[g] = ws[WS_BIAS + g * 256 + tid];

    float c = 0.f, h_last = 0.f;
    hS[tid] = 0.f;
    const float* T2b = T2 + (long)b * 1024 * 64;
    if (tid < 16) ((float4*)t2iS[0])[tid] = ((const float4*)T2b)[tid];
    __syncthreads();

    float* outB = out + (long)b * 1024 * 256;
    const float4* hS4 = (const float4*)hS;

    for (int t = 0; t < 1024; ++t) {
        // ---- stage AB: partial t2h over this wave's h chunk
        float p0 = 0.f, p1 = 0.f, p2 = 0.f, p3 = 0.f;
#pragma unroll
        for (int k = 0; k < 16; ++k) {
            float4 hv = hS4[(abq << 4) + k];
            p0 += hv.x * a1r[4 * k + 0];
            p1 += hv.y * a1r[4 * k + 1];
            p2 += hv.z * a1r[4 * k + 2];
            p3 += hv.w * a1r[4 * k + 3];
        }
        part[abOut * 4 + abq] = (p0 + p1) + (p2 + p3);

        // prefetch next step's T2ih into registers (latency hidden across barriers)
        float4 pre;
        bool do_pre = (tid < 16) && (t + 1 < 1024);
        if (do_pre) pre = ((const float4*)(T2b + (t + 1) * 64))[tid];

        __syncthreads();  // B

        if (tid < 64) {
            float4 v = ((const float4*)part)[tid];
            t2hS[tid] = (v.x + v.y) + (v.z + v.w);
        }
        if (do_pre) ((float4*)t2iS[(t + 1) & 1])[tid] = pre;

        __syncthreads();  // C

        // ---- stage CD: gates[g][tid] = bias + t2h.C2h + t2i.C2ih
        const float* t2i = t2iS[t & 1];
        float accg[4];
#pragma unroll
        for (int g = 0; g < 4; ++g) {
            float a = biasr[g];
#pragma unroll
            for (int k = 0; k < 4; ++k) {
                float4 th = ((const float4*)t2hS)[g * 4 + k];
                float4 ti = ((const float4*)t2i)[g * 4 + k];
                int u = g * 16 + k * 4;
                a += th.x * c2hr[u + 0] + th.y * c2hr[u + 1] +
                     th.z * c2hr[u + 2] + th.w * c2hr[u + 3];
                a += ti.x * c2ir[u + 0] + ti.y * c2ir[u + 1] +
                     ti.z * c2ir[u + 2] + ti.w * c2ir[u + 3];
            }
            accg[g] = a;
        }
        float ig = fsig(accg[0]);
        float fg = fsig(accg[1]);
        float gg = ftanh_(accg[2]);
        float og = fsig(accg[3]);
        c = fg * c + ig * gg;
        float h = og * ftanh_(c);
        h_last = h;
        outB[t * 256 + tid] = h;
        hS[tid] = h;

        __syncthreads();  // A (protects hS for next step's AB reads)
    }

    // final (h, c): concat after output region
    out[16777216 + b * 256 + tid] = h_last;
    out[16777216 + 16384 + b * 256 + tid] = c;
}

extern "C" void kernel_launch(void* const* d_in, const int* in_sizes, int n_in,
                              void* d_out, int out_size, void* d_ws, size_t ws_size,
                              hipStream_t stream) {
    const float* x     = (const float*)d_in[0];
    const float* ih_g0 = (const float*)d_in[1];
    const float* ih_g1 = (const float*)d_in[2];
    const float* ih_g2 = (const float*)d_in[3];
    const float* ih_g3 = (const float*)d_in[4];
    const float* ih_b  = (const float*)d_in[5];
    const float* hh_g0 = (const float*)d_in[6];
    const float* hh_g1 = (const float*)d_in[7];
    const float* hh_g2 = (const float*)d_in[8];
    const float* hh_g3 = (const float*)d_in[9];
    const float* hh_b  = (const float*)d_in[10];
    float* out = (float*)d_out;
    float* ws  = (float*)d_ws;

    // K0: compose cores (33792 outputs)
    k_compose<<<132, 256, 0, stream>>>(ih_g0, ih_g1, ih_g2, ih_g3, ih_b,
                                       hh_g0, hh_g1, hh_g2, hh_g3, hh_b, ws);
    // K1: T2ih for all 65536 rows
    k_t2ih<<<1024, 256, 0, stream>>>(x, ws, ws + WS_T2);
    // K2: recurrence
    k_lstm<<<64, 256, 0, stream>>>(ws, ws + WS_T2, out);
}

// Round 2
// 1349.820 us; speedup vs baseline: 1.1429x; 1.1429x over previous
//
#include <hip/hip_runtime.h>

// TT-LSTM: B=64, T=1024, D=H=256, F=16, R=16, NG=4.
// ws layout (floats):
//   A1ihT [64][256]  @ 0       ([g*16+s][m*16+n], composed g0*g1 for ih)
//   A1hT  [64][256]  @ 16384   (same for hh)
//   C2ih  [64][256]  @ 32768   ([g*16+s][o*16+p], composed g2*g3 for ih)
//   C2h   [64][256]  @ 49152
//   biasS [4][256]   @ 65536   (ih_bias + hh_bias)
//   T2ih  [65536][64]@ 66560   (first-stage ih contraction for all rows)

#define WS_A1I 0
#define WS_A1H 16384
#define WS_C2I 32768
#define WS_C2H 49152
#define WS_BIAS 65536
#define WS_T2 66560

__device__ __forceinline__ float fsig(float x) {
    float e = __builtin_amdgcn_exp2f(-1.442695040888963f * x);
    return __builtin_amdgcn_rcpf(1.0f + e);
}
__device__ __forceinline__ float ftanh_(float x) {
    float e = __builtin_amdgcn_exp2f(2.885390081777926f * x);
    return 1.0f - 2.0f * __builtin_amdgcn_rcpf(1.0f + e);
}

// Workgroup barrier that only drains LDS (lgkmcnt), NOT global stores/loads
// (vmcnt). __syncthreads() would emit s_waitcnt vmcnt(0) and serialize on the
// per-step global out-store + T2 prefetch. "memory" clobber = compiler fence.
__device__ __forceinline__ void bar_lds() {
    asm volatile("s_waitcnt lgkmcnt(0)\n\ts_barrier" ::: "memory");
}

// ---------------- K0: compose TT cores ----------------
__global__ void k_compose(const float* __restrict__ g0i, const float* __restrict__ g1i,
                          const float* __restrict__ g2i, const float* __restrict__ g3i,
                          const float* __restrict__ bi,
                          const float* __restrict__ g0h, const float* __restrict__ g1h,
                          const float* __restrict__ g2h, const float* __restrict__ g3h,
                          const float* __restrict__ bh,
                          float* __restrict__ ws) {
    int id = blockIdx.x * 256 + threadIdx.x;
    if (id < 16384) {
        int g = id >> 12, s = (id >> 8) & 15, mn = id & 255;
        int m = mn >> 4, n = mn & 15;
        float aI = 0.f, aH = 0.f;
        for (int r = 0; r < 16; ++r) {
            aI += g0i[(g * 16 + m) * 16 + r] * g1i[((g * 16 + r) * 16 + n) * 16 + s];
            aH += g0h[(g * 16 + m) * 16 + r] * g1h[((g * 16 + r) * 16 + n) * 16 + s];
        }
        ws[WS_A1I + (g * 16 + s) * 256 + mn] = aI;
        ws[WS_A1H + (g * 16 + s) * 256 + mn] = aH;
    } else if (id < 32768) {
        int id2 = id - 16384;
        int g = id2 >> 12, s = (id2 >> 8) & 15, j = id2 & 255;
        int o = j >> 4, p = j & 15;
        float aI = 0.f, aH = 0.f;
        for (int t = 0; t < 16; ++t) {
            aI += g2i[((g * 16 + s) * 16 + o) * 16 + t] * g3i[(g * 16 + t) * 16 + p];
            aH += g2h[((g * 16 + s) * 16 + o) * 16 + t] * g3h[(g * 16 + t) * 16 + p];
        }
        ws[WS_C2I + (g * 16 + s) * 256 + j] = aI;
        ws[WS_C2H + (g * 16 + s) * 256 + j] = aH;
    } else if (id < 33792) {
        int id2 = id - 32768;
        ws[WS_BIAS + id2] = bi[id2] + bh[id2];
    }
}

// ---------------- K1: T2ih = X @ A1ih ----------------
__global__ __launch_bounds__(256, 1) void k_t2ih(const float* __restrict__ x,
                                                 const float* __restrict__ ws,
                                                 float* __restrict__ T2) {
    __shared__ __align__(16) float Xs[64 * 256];
    __shared__ __align__(16) float As[64 * 256];
    const int tid = threadIdx.x;
    const long r0 = (long)blockIdx.x * 64;

    const float4* X4 = (const float4*)(x + r0 * 256);
    const float4* A4 = (const float4*)(ws + WS_A1I);
    float4* Xs4 = (float4*)Xs;
    float4* As4 = (float4*)As;
#pragma unroll
    for (int k = 0; k < 16; ++k) {
        int idx = tid + k * 256;
        Xs4[idx] = X4[idx];
        int row = idx >> 6, c = idx & 63;
        As4[(row << 6) | (c ^ (row & 15))] = A4[idx];
    }
    __syncthreads();

    const int ro = tid & 15;
    const int q  = tid >> 4;
    float acc[4][4];
#pragma unroll
    for (int i = 0; i < 4; ++i)
#pragma unroll
        for (int j = 0; j < 4; ++j) acc[i][j] = 0.f;

    for (int mn4 = 0; mn4 < 64; ++mn4) {
        float4 a[4], xv[4];
#pragma unroll
        for (int j = 0; j < 4; ++j) {
            int row = ro * 4 + j;
            a[j] = As4[(row << 6) | (mn4 ^ (row & 15))];
        }
#pragma unroll
        for (int i = 0; i < 4; ++i) xv[i] = Xs4[((q * 4 + i) << 6) | mn4];
#pragma unroll
        for (int i = 0; i < 4; ++i)
#pragma unroll
            for (int j = 0; j < 4; ++j)
                acc[i][j] += xv[i].x * a[j].x + xv[i].y * a[j].y +
                             xv[i].z * a[j].z + xv[i].w * a[j].w;
    }
#pragma unroll
    for (int i = 0; i < 4; ++i)
#pragma unroll
        for (int j = 0; j < 4; ++j)
            T2[(r0 + q * 4 + i) * 64 + ro * 4 + j] = acc[i][j];
}

// ---------------- K2: recurrent LSTM ----------------
// 64 blocks (one per batch row) x 256 threads (4 waves), 1024 sequential steps.
// wave w, lane l. Weights pinned in VGPRs via opaque asm:
//   a1r[64]  : A1h[u=l][h-chunk 64w..64w+64)      (AB stage)
//   c2hr/c2ir[64]: C2{h,i}[16w+s][j=64k+l], s<16,k<4  (CD stage, gate g=w)
__global__ __launch_bounds__(256, 1) void k_lstm(const float* __restrict__ ws,
                                                 const float* __restrict__ T2,
                                                 float* __restrict__ out) {
    __shared__ __align__(16) float hS[256];
    __shared__ __align__(16) float part[4 * 64];    // [w][u]
    __shared__ __align__(16) float t2hS[64];
    __shared__ __align__(16) float t2iS[2][64];
    __shared__ __align__(16) float gS[4 * 256];     // [g][j]

    const int tid = threadIdx.x;
    const int w = tid >> 6;
    const int lane = tid & 63;
    const int b = blockIdx.x;

    // ---- one-time weight loads ----
    float a1r[64];
    {
        const float4* A1h4 = (const float4*)(ws + WS_A1H);
#pragma unroll
        for (int k = 0; k < 16; ++k) {
            float4 v = A1h4[lane * 64 + w * 16 + k];
            a1r[4 * k + 0] = v.x; a1r[4 * k + 1] = v.y;
            a1r[4 * k + 2] = v.z; a1r[4 * k + 3] = v.w;
        }
    }
    float c2hr[64], c2ir[64], biasr[4];
#pragma unroll
    for (int q = 0; q < 4; ++q)
#pragma unroll
        for (int m = 0; m < 4; ++m)
#pragma unroll
            for (int k = 0; k < 4; ++k) {
                int u = 16 * w + 4 * q + m;
                c2hr[q * 16 + m * 4 + k] = ws[WS_C2H + u * 256 + 64 * k + lane];
                c2ir[q * 16 + m * 4 + k] = ws[WS_C2I + u * 256 + 64 * k + lane];
            }
#pragma unroll
    for (int k = 0; k < 4; ++k) biasr[k] = ws[WS_BIAS + w * 256 + 64 * k + lane];

    // Pin all weights in VGPRs — prevents the compiler from demoting them to
    // per-iteration global re-loads (round 1: VGPR_Count=124 < 196 floats).
#pragma unroll
    for (int i = 0; i < 64; ++i)
        asm volatile("" : "+v"(a1r[i]), "+v"(c2hr[i]), "+v"(c2ir[i]));
#pragma unroll
    for (int i = 0; i < 4; ++i) asm volatile("" : "+v"(biasr[i]));

    float c = 0.f, h_last = 0.f;
    hS[tid] = 0.f;
    const float* T2b = T2 + (long)b * 1024 * 64;
    float4 preA = make_float4(0.f, 0.f, 0.f, 0.f);
    float4 preB = make_float4(0.f, 0.f, 0.f, 0.f);
    if (tid < 16) {
        ((float4*)t2iS[0])[tid] = ((const float4*)T2b)[tid];
        preA = ((const float4*)(T2b + 64))[tid];    // T2[t=1]
    }
    bar_lds();

    float* outB = out + (long)b * 1024 * 256;
    const float4* hS4 = (const float4*)hS;
    const float4* t2hv = (const float4*)t2hS;

    auto body = [&](int t, float4& preW, float4& preL) {
        // ---- AB: partial t2h[lane] over h-chunk w
        float p0 = 0.f, p1 = 0.f, p2 = 0.f, p3 = 0.f;
#pragma unroll
        for (int k = 0; k < 16; ++k) {
            float4 hv = hS4[w * 16 + k];            // wave-uniform broadcast
            p0 += hv.x * a1r[4 * k + 0];
            p1 += hv.y * a1r[4 * k + 1];
            p2 += hv.z * a1r[4 * k + 2];
            p3 += hv.w * a1r[4 * k + 3];
        }
        part[w * 64 + lane] = (p0 + p1) + (p2 + p3);   // conflict-free

        if ((tid < 16) && (t + 2 < 1024))
            preL = ((const float4*)(T2b + (t + 2) * 64))[tid];

        bar_lds();  // B

        if (tid < 64)
            t2hS[tid] = (part[tid] + part[64 + tid]) +
                        (part[128 + tid] + part[192 + tid]);
        if ((tid < 16) && (t + 1 < 1024))
            ((float4*)t2iS[(t + 1) & 1])[tid] = preW;  // 1-step-old load: no stall

        bar_lds();  // C

        // ---- CD: gate g=w, hidden j=64k+lane, block-diagonal u-slice 16w..16w+16
        const float4* t2iv = (const float4*)t2iS[t & 1];
        float acc0 = biasr[0], acc1 = biasr[1], acc2 = biasr[2], acc3 = biasr[3];
#pragma unroll
        for (int q = 0; q < 4; ++q) {
            float4 th = t2hv[w * 4 + q];            // wave-uniform broadcast
            float4 ti = t2iv[w * 4 + q];
            int o = q * 16;
            acc0 += th.x * c2hr[o + 0]  + th.y * c2hr[o + 4]  + th.z * c2hr[o + 8]  + th.w * c2hr[o + 12]
                  + ti.x * c2ir[o + 0]  + ti.y * c2ir[o + 4]  + ti.z * c2ir[o + 8]  + ti.w * c2ir[o + 12];
            acc1 += th.x * c2hr[o + 1]  + th.y * c2hr[o + 5]  + th.z * c2hr[o + 9]  + th.w * c2hr[o + 13]
                  + ti.x * c2ir[o + 1]  + ti.y * c2ir[o + 5]  + ti.z * c2ir[o + 9]  + ti.w * c2ir[o + 13];
            acc2 += th.x * c2hr[o + 2]  + th.y * c2hr[o + 6]  + th.z * c2hr[o + 10] + th.w * c2hr[o + 14]
                  + ti.x * c2ir[o + 2]  + ti.y * c2ir[o + 6]  + ti.z * c2ir[o + 10] + ti.w * c2ir[o + 14];
            acc3 += th.x * c2hr[o + 3]  + th.y * c2hr[o + 7]  + th.z * c2hr[o + 11] + th.w * c2hr[o + 15]
                  + ti.x * c2ir[o + 3]  + ti.y * c2ir[o + 7]  + ti.z * c2ir[o + 11] + ti.w * c2ir[o + 15];
        }
        gS[w * 256 + 0 * 64 + lane] = acc0;
        gS[w * 256 + 1 * 64 + lane] = acc1;
        gS[w * 256 + 2 * 64 + lane] = acc2;
        gS[w * 256 + 3 * 64 + lane] = acc3;

        bar_lds();  // D

        // ---- cell update: hidden j = tid
        float gi = gS[0 * 256 + tid];
        float gf = gS[1 * 256 + tid];
        float gg = gS[2 * 256 + tid];
        float go = gS[3 * 256 + tid];
        float ig = fsig(gi), fg = fsig(gf), gv = ftanh_(gg), og = fsig(go);
        c = fg * c + ig * gv;
        float h = og * ftanh_(c);
        h_last = h;
        outB[t * 256 + tid] = h;                    // never drained (bar_lds)
        hS[tid] = h;

        bar_lds();  // A
    };

    for (int t = 0; t < 1024; t += 2) {
        body(t, preA, preB);
        body(t + 1, preB, preA);
    }

    out[16777216 + b * 256 + tid] = h_last;
    out[16777216 + 16384 + b * 256 + tid] = c;
}

extern "C" void kernel_launch(void* const* d_in, const int* in_sizes, int n_in,
                              void* d_out, int out_size, void* d_ws, size_t ws_size,
                              hipStream_t stream) {
    const float* x     = (const float*)d_in[0];
    const float* ih_g0 = (const float*)d_in[1];
    const float* ih_g1 = (const float*)d_in[2];
    const float* ih_g2 = (const float*)d_in[3];
    const float* ih_g3 = (const float*)d_in[4];
    const float* ih_b  = (const float*)d_in[5];
    const float* hh_g0 = (const float*)d_in[6];
    const float* hh_g1 = (const float*)d_in[7];
    const float* hh_g2 = (const float*)d_in[8];
    const float* hh_g3 = (const float*)d_in[9];
    const float* hh_b  = (const float*)d_in[10];
    float* out = (float*)d_out;
    float* ws  = (float*)d_ws;

    k_compose<<<132, 256, 0, stream>>>(ih_g0, ih_g1, ih_g2, ih_g3, ih_b,
                                       hh_g0, hh_g1, hh_g2, hh_g3, hh_b, ws);
    k_t2ih<<<1024, 256, 0, stream>>>(x, ws, ws + WS_T2);
    k_lstm<<<64, 256, 0, stream>>>(ws, ws + WS_T2, out);
}

// Round 3
// 1024.896 us; speedup vs baseline: 1.5052x; 1.3170x over previous
//
#include <hip/hip_runtime.h>

// TT-LSTM: B=64, T=1024, D=H=256, F=16, R=16, NG=4.
// ws layout (floats):
//   A1ihT [64][256]  @ 0       ([g*16+s][m*16+n], composed g0*g1 for ih)
//   A1hT  [64][256]  @ 16384   (same for hh)
//   C2ih  [64][256]  @ 32768   ([g*16+s][o*16+p], composed g2*g3 for ih)
//   C2h   [64][256]  @ 49152
//   biasS [4][256]   @ 65536   (ih_bias + hh_bias)
//   T2ih  [65536][64]@ 66560   (first-stage ih contraction for all rows)

#define WS_A1I 0
#define WS_A1H 16384
#define WS_C2I 32768
#define WS_C2H 49152
#define WS_BIAS 65536
#define WS_T2 66560

__device__ __forceinline__ float fsig(float x) {
    float e = __builtin_amdgcn_exp2f(-1.442695040888963f * x);
    return __builtin_amdgcn_rcpf(1.0f + e);
}
__device__ __forceinline__ float ftanh_(float x) {
    float e = __builtin_amdgcn_exp2f(2.885390081777926f * x);
    return 1.0f - 2.0f * __builtin_amdgcn_rcpf(1.0f + e);
}

// Barrier draining LDS only (lgkmcnt), NOT global loads/stores (vmcnt):
// per-step global out-store and T2 prefetch stay in flight across barriers.
__device__ __forceinline__ void bar_lds() {
    asm volatile("s_waitcnt lgkmcnt(0)\n\ts_barrier" ::: "memory");
}

// ---------------- K0: compose TT cores ----------------
__global__ void k_compose(const float* __restrict__ g0i, const float* __restrict__ g1i,
                          const float* __restrict__ g2i, const float* __restrict__ g3i,
                          const float* __restrict__ bi,
                          const float* __restrict__ g0h, const float* __restrict__ g1h,
                          const float* __restrict__ g2h, const float* __restrict__ g3h,
                          const float* __restrict__ bh,
                          float* __restrict__ ws) {
    int id = blockIdx.x * 256 + threadIdx.x;
    if (id < 16384) {
        int g = id >> 12, s = (id >> 8) & 15, mn = id & 255;
        int m = mn >> 4, n = mn & 15;
        float aI = 0.f, aH = 0.f;
        for (int r = 0; r < 16; ++r) {
            aI += g0i[(g * 16 + m) * 16 + r] * g1i[((g * 16 + r) * 16 + n) * 16 + s];
            aH += g0h[(g * 16 + m) * 16 + r] * g1h[((g * 16 + r) * 16 + n) * 16 + s];
        }
        ws[WS_A1I + (g * 16 + s) * 256 + mn] = aI;
        ws[WS_A1H + (g * 16 + s) * 256 + mn] = aH;
    } else if (id < 32768) {
        int id2 = id - 16384;
        int g = id2 >> 12, s = (id2 >> 8) & 15, j = id2 & 255;
        int o = j >> 4, p = j & 15;
        float aI = 0.f, aH = 0.f;
        for (int t = 0; t < 16; ++t) {
            aI += g2i[((g * 16 + s) * 16 + o) * 16 + t] * g3i[(g * 16 + t) * 16 + p];
            aH += g2h[((g * 16 + s) * 16 + o) * 16 + t] * g3h[(g * 16 + t) * 16 + p];
        }
        ws[WS_C2I + (g * 16 + s) * 256 + j] = aI;
        ws[WS_C2H + (g * 16 + s) * 256 + j] = aH;
    } else if (id < 33792) {
        int id2 = id - 32768;
        ws[WS_BIAS + id2] = bi[id2] + bh[id2];
    }
}

// ---------------- K1: T2ih = X @ A1ih ----------------
// Both tiles xor-swizzled by (row&15) on the f4-column -> conflict-free reads.
// 128 KB LDS total at 2 blocks/CU.
__global__ __launch_bounds__(256, 2) void k_t2ih(const float* __restrict__ x,
                                                 const float* __restrict__ ws,
                                                 float* __restrict__ T2) {
    __shared__ __align__(16) float Xs[64 * 256];
    __shared__ __align__(16) float As[64 * 256];
    const int tid = threadIdx.x;
    const long r0 = (long)blockIdx.x * 64;

    const float4* X4 = (const float4*)(x + r0 * 256);
    const float4* A4 = (const float4*)(ws + WS_A1I);
    float4* Xs4 = (float4*)Xs;
    float4* As4 = (float4*)As;
#pragma unroll
    for (int k = 0; k < 16; ++k) {
        int idx = tid + k * 256;
        int row = idx >> 6, c = idx & 63;
        int sw = (row << 6) | (c ^ (row & 15));
        Xs4[sw] = X4[idx];
        As4[sw] = A4[idx];
    }
    __syncthreads();

    const int ro = tid & 15;
    const int q  = tid >> 4;
    float acc[4][4];
#pragma unroll
    for (int i = 0; i < 4; ++i)
#pragma unroll
        for (int j = 0; j < 4; ++j) acc[i][j] = 0.f;

    for (int mn4 = 0; mn4 < 64; ++mn4) {
        float4 a[4], xv[4];
#pragma unroll
        for (int j = 0; j < 4; ++j) {
            int row = ro * 4 + j;
            a[j] = As4[(row << 6) | (mn4 ^ (row & 15))];
        }
#pragma unroll
        for (int i = 0; i < 4; ++i) {
            int row = q * 4 + i;
            xv[i] = Xs4[(row << 6) | (mn4 ^ (row & 15))];
        }
#pragma unroll
        for (int i = 0; i < 4; ++i)
#pragma unroll
            for (int j = 0; j < 4; ++j)
                acc[i][j] += xv[i].x * a[j].x + xv[i].y * a[j].y +
                             xv[i].z * a[j].z + xv[i].w * a[j].w;
    }
#pragma unroll
    for (int i = 0; i < 4; ++i)
#pragma unroll
        for (int j = 0; j < 4; ++j)
            T2[(r0 + q * 4 + i) * 64 + ro * 4 + j] = acc[i][j];
}

// ---------------- K2: recurrent LSTM ----------------
// 64 blocks x 512 threads (8 waves, 2/SIMD), 1024 steps, 3 barriers/step.
// Per-thread weights (~98 floats, fits in VGPRs):
//   AB: u=8w+(lane&7), mn-chunk (lane>>3)*32  -> a1r[32]; in-wave shfl reduce.
//   CD: gate g=w>>1, j0=(w&1)*64+lane, j1=j0+128 -> c2{h,i}{0,1}[16].
// hS stored xor-swizzled so AB's 8-distinct-address reads are conflict-free.
__global__ __launch_bounds__(512, 2) void k_lstm(const float* __restrict__ ws,
                                                 const float* __restrict__ T2,
                                                 float* __restrict__ out) {
    __shared__ __align__(16) float hS[256];
    __shared__ __align__(16) float t2hS[64];
    __shared__ __align__(16) float t2iS[2][64];
    __shared__ __align__(16) float gS[4 * 256];

    const int tid  = threadIdx.x;
    const int w    = tid >> 6;
    const int lane = tid & 63;
    const int b    = blockIdx.x;

    // ---- AB weights ----
    const int ch   = lane >> 3;
    const int u_ab = 8 * w + (lane & 7);
    float a1r[32];
    {
        const float4* A1h4 = (const float4*)(ws + WS_A1H);
#pragma unroll
        for (int k = 0; k < 8; ++k) {
            float4 v = A1h4[u_ab * 64 + ch * 8 + k];
            a1r[4 * k + 0] = v.x; a1r[4 * k + 1] = v.y;
            a1r[4 * k + 2] = v.z; a1r[4 * k + 3] = v.w;
        }
    }

    // ---- CD weights ----
    const int g  = w >> 1;
    const int j0 = (w & 1) * 64 + lane;
    const int j1 = j0 + 128;
    float c2h0[16], c2h1[16], c2i0[16], c2i1[16];
#pragma unroll
    for (int s = 0; s < 16; ++s) {
        c2h0[s] = ws[WS_C2H + (16 * g + s) * 256 + j0];
        c2h1[s] = ws[WS_C2H + (16 * g + s) * 256 + j1];
        c2i0[s] = ws[WS_C2I + (16 * g + s) * 256 + j0];
        c2i1[s] = ws[WS_C2I + (16 * g + s) * 256 + j1];
    }
    float bias0 = ws[WS_BIAS + g * 256 + j0];
    float bias1 = ws[WS_BIAS + g * 256 + j1];

#pragma unroll
    for (int i = 0; i < 32; ++i) asm volatile("" : "+v"(a1r[i]));
#pragma unroll
    for (int i = 0; i < 16; ++i)
        asm volatile("" : "+v"(c2h0[i]), "+v"(c2h1[i]), "+v"(c2i0[i]), "+v"(c2i1[i]));

    float c = 0.f, h_last = 0.f;
    if (tid < 256) hS[tid] = 0.f;
    const float* T2b = T2 + (long)b * 1024 * 64;
    float4 preA = make_float4(0.f, 0.f, 0.f, 0.f);
    float4 preB = make_float4(0.f, 0.f, 0.f, 0.f);
    if (tid < 16) {
        ((float4*)t2iS[0])[tid] = ((const float4*)T2b)[tid];
        preA = ((const float4*)(T2b + 64))[tid];   // T2[t=1]
    }
    bar_lds();

    float* outB = out + (long)b * 1024 * 256;
    const float4* hS4  = (const float4*)hS;
    const float4* t2hv = (const float4*)t2hS;

    auto body = [&](int t, float4& preW, float4& preL) {
        // ---- AB: partial over mn-chunk ch, then in-wave reduce over ch ----
        float p0 = 0.f, p1 = 0.f, p2 = 0.f, p3 = 0.f;
#pragma unroll
        for (int k = 0; k < 8; ++k) {
            float4 hv = hS4[ch * 8 + ((k + ch) & 7)];   // swizzled, conflict-free
            p0 += hv.x * a1r[4 * k + 0];
            p1 += hv.y * a1r[4 * k + 1];
            p2 += hv.z * a1r[4 * k + 2];
            p3 += hv.w * a1r[4 * k + 3];
        }
        float t2v = (p0 + p1) + (p2 + p3);
        if ((tid < 16) && (t + 2 < 1024))
            preL = ((const float4*)(T2b + (t + 2) * 64))[tid];
        t2v += __shfl_xor(t2v, 8);
        t2v += __shfl_xor(t2v, 16);
        t2v += __shfl_xor(t2v, 32);
        if (lane < 8) t2hS[8 * w + lane] = t2v;

        bar_lds();  // 1: t2hS ready

        if ((tid < 16) && (t + 1 < 1024))
            ((float4*)t2iS[(t + 1) & 1])[tid] = preW;   // other buffer: no race

        // ---- CD: gate g, hidden j0/j1 ----
        const float4* t2iv = (const float4*)t2iS[t & 1];
        float acc0 = bias0, acc1 = bias1;
#pragma unroll
        for (int q = 0; q < 4; ++q) {
            float4 th = t2hv[g * 4 + q];                // wave-uniform broadcast
            float4 ti = t2iv[g * 4 + q];
            acc0 += th.x * c2h0[4*q+0] + th.y * c2h0[4*q+1] + th.z * c2h0[4*q+2] + th.w * c2h0[4*q+3]
                  + ti.x * c2i0[4*q+0] + ti.y * c2i0[4*q+1] + ti.z * c2i0[4*q+2] + ti.w * c2i0[4*q+3];
            acc1 += th.x * c2h1[4*q+0] + th.y * c2h1[4*q+1] + th.z * c2h1[4*q+2] + th.w * c2h1[4*q+3]
                  + ti.x * c2i1[4*q+0] + ti.y * c2i1[4*q+1] + ti.z * c2i1[4*q+2] + ti.w * c2i1[4*q+3];
        }
        gS[g * 256 + j0] = acc0;
        gS[g * 256 + j1] = acc1;

        bar_lds();  // 2: gS ready

        // ---- cell update: j = tid (waves 0-3) ----
        if (tid < 256) {
            float gi = gS[tid], gf = gS[256 + tid], gg = gS[512 + tid], go = gS[768 + tid];
            float ig = fsig(gi), fg = fsig(gf), gv = ftanh_(gg), og = fsig(go);
            c = fg * c + ig * gv;
            float h = og * ftanh_(c);
            h_last = h;
            outB[t * 256 + tid] = h;                    // never drained (bar_lds)
            int chj = tid >> 5, kj = (tid >> 2) & 7;
            hS[chj * 32 + (((kj + chj) & 7) << 2) + (tid & 3)] = h;  // swizzled
        }

        bar_lds();  // 3: hS ready
    };

    for (int t = 0; t < 1024; t += 2) {
        body(t, preA, preB);
        body(t + 1, preB, preA);
    }

    if (tid < 256) {
        out[16777216 + b * 256 + tid] = h_last;
        out[16777216 + 16384 + b * 256 + tid] = c;
    }
}

extern "C" void kernel_launch(void* const* d_in, const int* in_sizes, int n_in,
                              void* d_out, int out_size, void* d_ws, size_t ws_size,
                              hipStream_t stream) {
    const float* x     = (const float*)d_in[0];
    const float* ih_g0 = (const float*)d_in[1];
    const float* ih_g1 = (const float*)d_in[2];
    const float* ih_g2 = (const float*)d_in[3];
    const float* ih_g3 = (const float*)d_in[4];
    const float* ih_b  = (const float*)d_in[5];
    const float* hh_g0 = (const float*)d_in[6];
    const float* hh_g1 = (const float*)d_in[7];
    const float* hh_g2 = (const float*)d_in[8];
    const float* hh_g3 = (const float*)d_in[9];
    const float* hh_b  = (const float*)d_in[10];
    float* out = (float*)d_out;
    float* ws  = (float*)d_ws;

    k_compose<<<132, 256, 0, stream>>>(ih_g0, ih_g1, ih_g2, ih_g3, ih_b,
                                       hh_g0, hh_g1, hh_g2, hh_g3, hh_b, ws);
    k_t2ih<<<1024, 256, 0, stream>>>(x, ws, ws + WS_T2);
    k_lstm<<<64, 512, 0, stream>>>(ws, ws + WS_T2, out);
}